// Round 8
// baseline (62.732 us; speedup 1.0000x reference)
//
#include <hip/hip_runtime.h>

// Bilinear warp: out[b,c,h,w] = bilerp(img[b,c], (w+flo[b,0,h,w], h+flo[b,1,h,w]))
// img: [8,16,512,512] f32, flo: [8,2,512,512] f32, out: [8,16,512,512] f32.
//
// Round 8: law dur ~= 39us + 22.7us/M-wave-VMEM fits R2/R4/R6/R7 exactly.
// Cut VMEM/wave 66 -> 50: tile 64x32 (512 thr, 8 waves), window 48x84 = 4032
// floats = 16 chunks -> 2 stage instr/wave/ch (was 3). Top halo 8->7 rows
// (P~1e-12; badmask+fixup keeps correctness exact). LDS 2x16KB = 32KB ->
// 4 blocks/CU = 32 waves. Also: regular stores (drop NT) to test whether NT
// writes depress effective BW (the 39us intercept = 209MB @ 5.4TB/s).

#define BB 8
#define CC 16
#define HH 512
#define WW 512
#define HWSZ (HH * WW)

#define TW 64                    // output tile width
#define TH 32                    // output tile height
#define TILES_X (WW / TW)        // 8
#define TILES_Y (HH / TH)        // 16
#define TPI (TILES_X * TILES_Y)  // 128
#define NBLOCKS (BB * TPI)       // 1024 = 8 * 128 (XCD k <- batch k, bijective)
#define NXCD 8

#define HALO_L 8                 // left/x halo (window cols 84 = 64+20)
#define HALO_T 7                 // top/y halo (window rows 48 = 32+7+9)
#define WIN_COLS 84
#define WIN_ROWS 48              // 4032 floats used; 16 chunks * 256 = 4096
#define PAD_FLOATS 4096          // 2 chunks per wave (8 waves), uniform

typedef float f4 __attribute__((ext_vector_type(4)));

__device__ __forceinline__ void gload_lds16(const float* g, float* l) {
    // per-lane global src; wave-uniform LDS base, HW writes base + lane*16
    __builtin_amdgcn_global_load_lds(
        (const __attribute__((address_space(1))) void*)g,
        (__attribute__((address_space(3))) void*)l,
        16, 0, 0);
}

__global__ __launch_bounds__(512) void warp_bilinear_kernel(
    const float* __restrict__ img,
    const float* __restrict__ flo,
    float* __restrict__ out)
{
    __shared__ __align__(16) float lds[2 * PAD_FLOATS];   // 32 KB

    // XCD swizzle: XCD k <- batch k, tiles top-to-bottom.
    int bid = blockIdx.x;
    int wk  = (bid % NXCD) * (NBLOCKS / NXCD) + bid / NXCD;
    int b    = wk / TPI;
    int tile = wk - b * TPI;
    int ty   = tile / TILES_X;
    int tx   = tile - ty * TILES_X;

    int t    = threadIdx.x;
    int wv   = t >> 6;               // wave id 0..7
    int lane = t & 63;

    int r   = t >> 4;                // row in tile 0..31
    int c4  = (t & 15) << 2;         // col in tile, 4 px per thread
    int h   = ty * TH + r;
    int w0  = tx * TW + c4;
    int hw  = h * WW + w0;
    int wx0 = tx * TW - HALO_L;      // staged window origin (may be <0)
    int wy0 = ty * TH - HALO_T;

    const float* imgb = img + (size_t)b * CC * HWSZ;
    float*       outb = out + (size_t)b * CC * HWSZ;

    // ---- staging setup: wave wv stages chunks {wv, wv+8} -------------------
    const float* srcp[2];            // per-lane global src, channel 0
    int          loff[2];            // LDS float offset (wave-uniform)
    #pragma unroll
    for (int j = 0; j < 2; ++j) {
        int k  = wv + 8 * j;
        int f  = k * 256 + lane * 4;            // float idx in window (mult of 4)
        int rr = f / 84;                         // window row (tail rows >=48 are
        int cc = f - rr * 84;                    //  never read; addr still valid)
        int gy = min(max(wy0 + rr, 0), HH - 1);  // clamp: halo/pad duplicates edge
        int gx = min(max(wx0 + cc, 0), WW - 4);  //  (only unread slots differ)
        srcp[j] = imgb + gy * WW + gx;
        loff[j] = k * 256;
    }

    auto stage = [&](int ch, int buf) {
        const size_t choff = (size_t)ch * HWSZ;
        float* lbase = lds + buf * PAD_FLOATS;
        #pragma unroll
        for (int j = 0; j < 2; ++j)
            gload_lds16(srcp[j] + choff, lbase + loff[j]);
    };

    stage(0, 0);   // channel 0 in flight before any dependent work

    // ---- per-pixel precompute (overlaps stage(0) latency) ------------------
    f4 fx4 = *(const f4*)(flo + (size_t)(b * 2 + 0) * HWSZ + hw);
    f4 fy4 = *(const f4*)(flo + (size_t)(b * 2 + 1) * HWSZ + hw);

    int   o0[4], o1[4];
    float wtx[4], wty[4], wbx[4], wby[4];
    int   badmask = 0;
    #pragma unroll
    for (int i = 0; i < 4; ++i) {
        float pos_x = (float)(w0 + i) + fx4[i];
        float pos_y = (float)h + fy4[i];

        float x0f = floorf(pos_x);
        float y0f = floorf(pos_y);
        float xw  = pos_x - x0f;     // weights from UNclamped floor (reference)
        float yw  = pos_y - y0f;

        int x0 = (int)fminf(fmaxf(x0f,        0.0f), (float)(WW - 1));
        int x1 = (int)fminf(fmaxf(x0f + 1.0f, 0.0f), (float)(WW - 1));
        int y0 = (int)fminf(fmaxf(y0f,        0.0f), (float)(HH - 1));
        int y1 = (int)fminf(fmaxf(y0f + 1.0f, 0.0f), (float)(HH - 1));

        int xb = min(x0, WW - 2);    // merged pair [xb, xb+1]

        float wa = (1.0f - xw) * (1.0f - yw);
        float wb = (1.0f - xw) * yw;
        float wc = xw * (1.0f - yw);
        float wd = xw * yw;

        float tx_ = (x0 == xb ? wa : 0.0f) + (x1 == xb ? wc : 0.0f);
        float bx_ = (x0 == xb ? wb : 0.0f) + (x1 == xb ? wd : 0.0f);
        wtx[i] = tx_;  wty[i] = (wa + wc) - tx_;
        wbx[i] = bx_;  wby[i] = (wb + wd) - bx_;

        bool ok = (xb >= wx0) & (xb + 1 <= wx0 + WIN_COLS - 1)
                & (y0 >= wy0) & (y1 <= wy0 + WIN_ROWS - 1);
        int a0 = (y0 - wy0) * WIN_COLS + (xb - wx0);
        int a1 = (y1 - wy0) * WIN_COLS + (xb - wx0);
        if (!ok) { a0 = 0; a1 = 0; badmask |= (1 << i); }  // safe dummy; fixed up
        o0[i] = a0;  o1[i] = a1;
    }

    // ---- channel loop: stage(c+1) || compute(c), counted vmcnt -------------
    // per-wave issue order: stage0 x2, flo x2 | iter c: stage(c+1) x2 ...
    // store(c) x1. Newer-than-stage(c) at the wait point:
    //   c==0 : stage(1) x2                       -> vmcnt(2) (flo already drained)
    //   1..14: store(c-1) + stage(c+1) x2 = 3    -> vmcnt(3)
    //   c==15: store(14)                          -> vmcnt(1)
    #pragma unroll
    for (int c = 0; c < CC; ++c) {
        const int buf = c & 1;
        if (c < CC - 1) stage(c + 1, buf ^ 1);

        if (c == 0)          asm volatile("s_waitcnt vmcnt(2)" ::: "memory");
        else if (c < CC - 1) asm volatile("s_waitcnt vmcnt(3)" ::: "memory");
        else                 asm volatile("s_waitcnt vmcnt(1)" ::: "memory");
        __builtin_amdgcn_sched_barrier(0);
        __builtin_amdgcn_s_barrier();          // buf[c&1] staged, all waves

        const float* cur = lds + buf * PAD_FLOATS;
        f4 v;
        #pragma unroll
        for (int i = 0; i < 4; ++i) {
            float t0 = cur[o0[i]];
            float t1 = cur[o0[i] + 1];
            float u0 = cur[o1[i]];
            float u1 = cur[o1[i] + 1];
            v[i] = wtx[i] * t0 + wty[i] * t1 + wbx[i] * u0 + wby[i] * u1;
        }
        *(f4*)(outb + (size_t)c * HWSZ + hw) = v;   // regular store (NT A/B)

        if (c < CC - 1) {
            asm volatile("s_waitcnt lgkmcnt(0)" ::: "memory"); // ds reads done
            __builtin_amdgcn_s_barrier();      // before buf is overwritten
        }
    }

    // ---- fixup: pixels whose footprint missed the staged window (~never) ---
    if (__builtin_expect(badmask != 0, 0)) {
        #pragma unroll
        for (int i = 0; i < 4; ++i) if (badmask & (1 << i)) {
            float fx = flo[(size_t)(b * 2 + 0) * HWSZ + hw + i];
            float fy = flo[(size_t)(b * 2 + 1) * HWSZ + hw + i];
            float pos_x = (float)(w0 + i) + fx;
            float pos_y = (float)h + fy;
            float x0f = floorf(pos_x), y0f = floorf(pos_y);
            float xw = pos_x - x0f,   yw = pos_y - y0f;
            int x0 = (int)fminf(fmaxf(x0f,        0.0f), (float)(WW - 1));
            int x1 = (int)fminf(fmaxf(x0f + 1.0f, 0.0f), (float)(WW - 1));
            int y0 = (int)fminf(fmaxf(y0f,        0.0f), (float)(HH - 1));
            int y1 = (int)fminf(fmaxf(y0f + 1.0f, 0.0f), (float)(HH - 1));
            float wa = (1.0f - xw) * (1.0f - yw);
            float wb = (1.0f - xw) * yw;
            float wc = xw * (1.0f - yw);
            float wd = xw * yw;
            for (int c = 0; c < CC; ++c) {
                const float* p = imgb + (size_t)c * HWSZ;
                float vv = wa * p[y0 * WW + x0] + wb * p[y1 * WW + x0]
                         + wc * p[y0 * WW + x1] + wd * p[y1 * WW + x1];
                outb[(size_t)c * HWSZ + hw + i] = vv;   // same thread: ordered
            }
        }
    }
}

extern "C" void kernel_launch(void* const* d_in, const int* in_sizes, int n_in,
                              void* d_out, int out_size, void* d_ws, size_t ws_size,
                              hipStream_t stream)
{
    const float* img = (const float*)d_in[0];
    const float* flo = (const float*)d_in[1];
    float*       out = (float*)d_out;

    warp_bilinear_kernel<<<NBLOCKS, 512, 0, stream>>>(img, flo, out);
}

// Round 9
// 50.814 us; speedup vs baseline: 1.2345x; 1.2345x over previous
//
#include <hip/hip_runtime.h>

// Bilinear warp: out[b,c,h,w] = bilerp(img[b,c], (w+flo[b,0,h,w], h+flo[b,1,h,w]))
// img: [8,16,512,512] f32, flo: [8,2,512,512] f32, out: [8,16,512,512] f32.
//
// Round 9: revert to R7 (50.6us, best) + ONE change: triple-buffer LDS ->
// ONE barrier per channel (was 2), staging 2 channels ahead. Per-iter:
// vmcnt(4) [stage(c) landed; store+stage(c+1) stay in flight] -> lgkmcnt(0)
// [this wave's reads of c-1 drained] -> s_barrier [all waves likewise] ->
// ds-compute(c) -> NT store(c) -> stage(c+2) into buf((c+2)%3)=buf((c-1)%3),
// which is safe: every wave passed the barrier after draining reads of c-1.
// flo loads issued FIRST so their implicit wait doesn't drain the prefetch.
// Geometry/window/chunks identical to R7; NT stores restored (R8 lesson).

#define BB 8
#define CC 16
#define HH 512
#define WW 512
#define HWSZ (HH * WW)

#define TW 64                    // output tile width
#define TH 16                    // output tile height
#define TILES_X (WW / TW)        // 8
#define TILES_Y (HH / TH)        // 32
#define TPI (TILES_X * TILES_Y)  // 256
#define NBLOCKS (BB * TPI)       // 2048 = 8 * 256 (XCD k <- batch k, bijective)
#define NXCD 8

#define HALO 8
#define WIN_COLS 84              // 64 + 20, = 21 float4 per row (never row-crossing)
#define WIN_ROWS 33              // 16 + 17
#define PAD_FLOATS 3072          // 12 chunks * 256 floats (covers 33*84=2772 + pad)
#define NBUF 3                   // triple buffer -> single barrier per channel

typedef float f4 __attribute__((ext_vector_type(4)));

__device__ __forceinline__ void gload_lds16(const float* g, float* l) {
    // per-lane global src; wave-uniform LDS base, HW writes base + lane*16
    __builtin_amdgcn_global_load_lds(
        (const __attribute__((address_space(1))) void*)g,
        (__attribute__((address_space(3))) void*)l,
        16, 0, 0);
}

__global__ __launch_bounds__(256) void warp_bilinear_kernel(
    const float* __restrict__ img,
    const float* __restrict__ flo,
    float* __restrict__ out)
{
    __shared__ __align__(16) float lds[NBUF * PAD_FLOATS];   // 36 KB

    // XCD swizzle: XCD k <- batch k, tiles top-to-bottom.
    int bid = blockIdx.x;
    int wk  = (bid % NXCD) * (NBLOCKS / NXCD) + bid / NXCD;
    int b    = wk / TPI;
    int tile = wk - b * TPI;
    int ty   = tile / TILES_X;
    int tx   = tile - ty * TILES_X;

    int t    = threadIdx.x;
    int wv   = t >> 6;               // wave id 0..3
    int lane = t & 63;

    int r   = t >> 4;                // row in tile 0..15
    int c4  = (t & 15) << 2;         // col in tile, 4 px per thread
    int h   = ty * TH + r;
    int w0  = tx * TW + c4;
    int hw  = h * WW + w0;
    int wx0 = tx * TW - HALO;        // staged window origin (may be <0)
    int wy0 = ty * TH - HALO;

    const float* imgb = img + (size_t)b * CC * HWSZ;
    float*       outb = out + (size_t)b * CC * HWSZ;

    // ---- flo loads FIRST: their implicit vmcnt wait (vmcnt(6)) leaves all
    //      6 prefetch stages in flight -------------------------------------
    f4 fx4 = *(const f4*)(flo + (size_t)(b * 2 + 0) * HWSZ + hw);
    f4 fy4 = *(const f4*)(flo + (size_t)(b * 2 + 1) * HWSZ + hw);

    // ---- staging chunk setup: wave wv stages chunks {wv, wv+4, wv+8} ------
    const float* srcp[3];            // per-lane global src, channel 0
    int          loff[3];            // LDS float offset (wave-uniform)
    #pragma unroll
    for (int j = 0; j < 3; ++j) {
        int k  = wv + 4 * j;
        int f  = k * 256 + lane * 4;           // float idx in window (mult of 4)
        int rr = f / 84;                        // window row (84 = 21*4, groups
        int cc = f - rr * 84;                   //  never straddle rows)
        int gy = min(max(wy0 + rr, 0), HH - 1); // clamp: pad/halo rows duplicate
        int gx = min(max(wx0 + cc, 0), WW - 4); //  edge data (only unread slots
        srcp[j] = imgb + gy * WW + gx;          //  differ from true window)
        loff[j] = k * 256;
    }

    auto stage = [&](int ch, int buf) {
        const size_t choff = (size_t)ch * HWSZ;
        float* lbase = lds + buf * PAD_FLOATS;
        #pragma unroll
        for (int j = 0; j < 3; ++j)
            gload_lds16(srcp[j] + choff, lbase + loff[j]);
    };

    stage(0, 0);   // 2-deep prefetch in flight before any dependent work
    stage(1, 1);

    // ---- per-pixel precompute (overlaps stage latency) --------------------
    int   o0[4], o1[4];
    float wtx[4], wty[4], wbx[4], wby[4];
    int   badmask = 0;
    #pragma unroll
    for (int i = 0; i < 4; ++i) {
        float pos_x = (float)(w0 + i) + fx4[i];
        float pos_y = (float)h + fy4[i];

        float x0f = floorf(pos_x);
        float y0f = floorf(pos_y);
        float xw  = pos_x - x0f;     // weights from UNclamped floor (reference)
        float yw  = pos_y - y0f;

        int x0 = (int)fminf(fmaxf(x0f,        0.0f), (float)(WW - 1));
        int x1 = (int)fminf(fmaxf(x0f + 1.0f, 0.0f), (float)(WW - 1));
        int y0 = (int)fminf(fmaxf(y0f,        0.0f), (float)(HH - 1));
        int y1 = (int)fminf(fmaxf(y0f + 1.0f, 0.0f), (float)(HH - 1));

        int xb = min(x0, WW - 2);    // merged pair [xb, xb+1]

        float wa = (1.0f - xw) * (1.0f - yw);
        float wb = (1.0f - xw) * yw;
        float wc = xw * (1.0f - yw);
        float wd = xw * yw;

        float tx_ = (x0 == xb ? wa : 0.0f) + (x1 == xb ? wc : 0.0f);
        float bx_ = (x0 == xb ? wb : 0.0f) + (x1 == xb ? wd : 0.0f);
        wtx[i] = tx_;  wty[i] = (wa + wc) - tx_;
        wbx[i] = bx_;  wby[i] = (wb + wd) - bx_;

        bool ok = (xb >= wx0) & (xb + 1 <= wx0 + WIN_COLS - 1)
                & (y0 >= wy0) & (y1 <= wy0 + WIN_ROWS - 1);
        int a0 = (y0 - wy0) * WIN_COLS + (xb - wx0);
        int a1 = (y1 - wy0) * WIN_COLS + (xb - wx0);
        if (!ok) { a0 = 0; a1 = 0; badmask |= (1 << i); }  // safe dummy; fixed up
        o0[i] = a0;  o1[i] = a1;
    }

    // ---- channel loop: ONE barrier per channel, stage 2 ahead -------------
    // Per-wave VMEM issue: [flo x2][stage0 x3][stage1 x3] | iter c: store(c),
    // stage(c+2) x3. At iter-c wait, newer than stage(c)'s last op:
    //   c==0 : stage(1) x3                    -> vmcnt(3)
    //   1..14: store(c-1) + stage(c+1) x3 = 4 -> vmcnt(4)  (store in flight)
    //   c==15: store(14)                      -> vmcnt(1)
    #pragma unroll
    for (int c = 0; c < CC; ++c) {
        const int buf = c % NBUF;

        if (c == 0)          asm volatile("s_waitcnt vmcnt(3)" ::: "memory");
        else if (c < CC - 1) asm volatile("s_waitcnt vmcnt(4)" ::: "memory");
        else                 asm volatile("s_waitcnt vmcnt(1)" ::: "memory");
        asm volatile("s_waitcnt lgkmcnt(0)" ::: "memory"); // reads of c-1 drained
        __builtin_amdgcn_sched_barrier(0);
        __builtin_amdgcn_s_barrier();   // all waves: stage(c) visible AND
                                        // everyone done reading buf((c-1)%3)

        const float* cur = lds + buf * PAD_FLOATS;
        f4 v;
        #pragma unroll
        for (int i = 0; i < 4; ++i) {
            float t0 = cur[o0[i]];
            float t1 = cur[o0[i] + 1];
            float u0 = cur[o1[i]];
            float u1 = cur[o1[i] + 1];
            v[i] = wtx[i] * t0 + wty[i] * t1 + wbx[i] * u0 + wby[i] * u1;
        }
        __builtin_nontemporal_store(v, (f4*)(outb + (size_t)c * HWSZ + hw));

        if (c + 2 < CC) stage(c + 2, (c + 2) % NBUF);  // overwrites buf((c-1)%3)
    }

    // ---- fixup: pixels whose footprint missed the staged window (~never) ---
    if (__builtin_expect(badmask != 0, 0)) {
        #pragma unroll
        for (int i = 0; i < 4; ++i) if (badmask & (1 << i)) {
            float fx = flo[(size_t)(b * 2 + 0) * HWSZ + hw + i];
            float fy = flo[(size_t)(b * 2 + 1) * HWSZ + hw + i];
            float pos_x = (float)(w0 + i) + fx;
            float pos_y = (float)h + fy;
            float x0f = floorf(pos_x), y0f = floorf(pos_y);
            float xw = pos_x - x0f,   yw = pos_y - y0f;
            int x0 = (int)fminf(fmaxf(x0f,        0.0f), (float)(WW - 1));
            int x1 = (int)fminf(fmaxf(x0f + 1.0f, 0.0f), (float)(WW - 1));
            int y0 = (int)fminf(fmaxf(y0f,        0.0f), (float)(HH - 1));
            int y1 = (int)fminf(fmaxf(y0f + 1.0f, 0.0f), (float)(HH - 1));
            float wa = (1.0f - xw) * (1.0f - yw);
            float wb = (1.0f - xw) * yw;
            float wc = xw * (1.0f - yw);
            float wd = xw * yw;
            for (int c = 0; c < CC; ++c) {
                const float* p = imgb + (size_t)c * HWSZ;
                float vv = wa * p[y0 * WW + x0] + wb * p[y1 * WW + x0]
                         + wc * p[y0 * WW + x1] + wd * p[y1 * WW + x1];
                outb[(size_t)c * HWSZ + hw + i] = vv;   // same thread: ordered
            }
        }
    }
}

extern "C" void kernel_launch(void* const* d_in, const int* in_sizes, int n_in,
                              void* d_out, int out_size, void* d_ws, size_t ws_size,
                              hipStream_t stream)
{
    const float* img = (const float*)d_in[0];
    const float* flo = (const float*)d_in[1];
    float*       out = (float*)d_out;

    warp_bilinear_kernel<<<NBLOCKS, 256, 0, stream>>>(img, flo, out);
}

// Round 11
// 49.926 us; speedup vs baseline: 1.2565x; 1.0178x over previous
//
#include <hip/hip_runtime.h>

// Bilinear warp: out[b,c,h,w] = bilerp(img[b,c], (w+flo[b,0,h,w], h+flo[b,1,h,w]))
// img: [8,16,512,512] f32, flo: [8,2,512,512] f32, out: [8,16,512,512] f32.
//
// Round 11: R9 base + corrected bank-conflict skew. R10's bug: per-group
// clamp shifted data WITHIN a 16B group at image edges. Now each LDS row rr
// stages the contiguous in-bounds window [ox, ox+87], ox = clamp(wx0-(rr&3),
// 0, W-88): groups are never clamped/shifted. Reads: s = xb - ox(r).
// Interior tiles: consecutive rows differ by (r&3) mod 4 in bank offset ->
// disjoint bank quarters -> ~2-way (free). Edge tile cols (tx=0,7): ox
// clamps to a constant -> unskewed there (accepted, 25% of blocks).

#define BB 8
#define CC 16
#define HH 512
#define WW 512
#define HWSZ (HH * WW)

#define TW 64                    // output tile width
#define TH 16                    // output tile height
#define TILES_X (WW / TW)        // 8
#define TILES_Y (HH / TH)        // 32
#define TPI (TILES_X * TILES_Y)  // 256
#define NBLOCKS (BB * TPI)       // 2048 = 8 * 256 (XCD k <- batch k, bijective)
#define NXCD 8

#define HALO 8
#define LDS_PITCH 88             // floats per LDS row; row rr holds global
                                 //  cols [ox(rr), ox(rr)+87]
#define OXMAX (WW - LDS_PITCH)   // 424
#define WIN_ROWS 33              // rows 0..32 fully staged (33*88=2904<=3072)
#define PAD_FLOATS 3072          // 12 chunks * 256 floats
#define NBUF 3                   // triple buffer, single barrier per channel

typedef float f4 __attribute__((ext_vector_type(4)));

__device__ __forceinline__ void gload_lds16(const float* g, float* l) {
    // per-lane global src; wave-uniform LDS base, HW writes base + lane*16
    __builtin_amdgcn_global_load_lds(
        (const __attribute__((address_space(1))) void*)g,
        (__attribute__((address_space(3))) void*)l,
        16, 0, 0);
}

__global__ __launch_bounds__(256) void warp_bilinear_kernel(
    const float* __restrict__ img,
    const float* __restrict__ flo,
    float* __restrict__ out)
{
    __shared__ __align__(16) float lds[NBUF * PAD_FLOATS];   // 36 KB

    // XCD swizzle: XCD k <- batch k, tiles top-to-bottom.
    int bid = blockIdx.x;
    int wk  = (bid % NXCD) * (NBLOCKS / NXCD) + bid / NXCD;
    int b    = wk / TPI;
    int tile = wk - b * TPI;
    int ty   = tile / TILES_X;
    int tx   = tile - ty * TILES_X;

    int t    = threadIdx.x;
    int wv   = t >> 6;               // wave id 0..3
    int lane = t & 63;

    int r   = t >> 4;                // row in tile 0..15
    int c4  = (t & 15) << 2;         // col in tile, 4 px per thread
    int h   = ty * TH + r;
    int w0  = tx * TW + c4;
    int hw  = h * WW + w0;
    int wx0 = tx * TW - HALO;        // nominal window origin (may be <0)
    int wy0 = ty * TH - HALO;

    const float* imgb = img + (size_t)b * CC * HWSZ;
    float*       outb = out + (size_t)b * CC * HWSZ;

    // ---- flo loads FIRST: their implicit wait leaves prefetch in flight ---
    f4 fx4 = *(const f4*)(flo + (size_t)(b * 2 + 0) * HWSZ + hw);
    f4 fy4 = *(const f4*)(flo + (size_t)(b * 2 + 1) * HWSZ + hw);

    // ---- staging chunk setup: wave wv stages chunks {wv, wv+4, wv+8} ------
    // LDS float f: rr = f/88, cc = f%88 (cc mult of 4; 88%4==0 so 16B groups
    // never straddle rows). Row rr holds cols [ox(rr), ox(rr)+87], all
    // in-bounds: group start ox+cc <= 424+84 = 508. No per-group clamp.
    const float* srcp[3];            // per-lane global src, channel 0
    int          loff[3];            // LDS float offset (wave-uniform)
    #pragma unroll
    for (int j = 0; j < 3; ++j) {
        int k  = wv + 4 * j;
        int f  = k * 256 + lane * 4;            // float idx in buffer (mult of 4)
        int rr = f / LDS_PITCH;                 // LDS row (rows >=33 unread)
        int cc = f - rr * LDS_PITCH;            // 0..84, mult of 4
        int gy = min(max(wy0 + rr, 0), HH - 1); // whole-row y clamp (consistent)
        int ox = min(max(wx0 - (rr & 3), 0), OXMAX);   // skewed row origin
        srcp[j] = imgb + gy * WW + ox + cc;
        loff[j] = k * 256;
    }

    auto stage = [&](int ch, int buf) {
        const size_t choff = (size_t)ch * HWSZ;
        float* lbase = lds + buf * PAD_FLOATS;
        #pragma unroll
        for (int j = 0; j < 3; ++j)
            gload_lds16(srcp[j] + choff, lbase + loff[j]);
    };

    stage(0, 0);   // 2-deep prefetch in flight before any dependent work
    stage(1, 1);

    // ---- per-pixel precompute (overlaps stage latency) --------------------
    int   o0[4], o1[4];
    float wtx[4], wty[4], wbx[4], wby[4];
    int   badmask = 0;
    #pragma unroll
    for (int i = 0; i < 4; ++i) {
        float pos_x = (float)(w0 + i) + fx4[i];
        float pos_y = (float)h + fy4[i];

        float x0f = floorf(pos_x);
        float y0f = floorf(pos_y);
        float xw  = pos_x - x0f;     // weights from UNclamped floor (reference)
        float yw  = pos_y - y0f;

        int x0 = (int)fminf(fmaxf(x0f,        0.0f), (float)(WW - 1));
        int x1 = (int)fminf(fmaxf(x0f + 1.0f, 0.0f), (float)(WW - 1));
        int y0 = (int)fminf(fmaxf(y0f,        0.0f), (float)(HH - 1));
        int y1 = (int)fminf(fmaxf(y0f + 1.0f, 0.0f), (float)(HH - 1));

        int xb = min(x0, WW - 2);    // merged pair [xb, xb+1]

        float wa = (1.0f - xw) * (1.0f - yw);
        float wb = (1.0f - xw) * yw;
        float wc = xw * (1.0f - yw);
        float wd = xw * yw;

        float tx_ = (x0 == xb ? wa : 0.0f) + (x1 == xb ? wc : 0.0f);
        float bx_ = (x0 == xb ? wb : 0.0f) + (x1 == xb ? wd : 0.0f);
        wtx[i] = tx_;  wty[i] = (wa + wc) - tx_;
        wbx[i] = bx_;  wby[i] = (wb + wd) - bx_;

        int r0 = y0 - wy0, r1 = y1 - wy0;
        int ox0 = min(max(wx0 - (r0 & 3), 0), OXMAX);   // same formula as stage
        int ox1 = min(max(wx0 - (r1 & 3), 0), OXMAX);
        int s0 = xb - ox0, s1 = xb - ox1;
        bool ok = (s0 >= 0) & (s0 <= LDS_PITCH - 2)
                & (s1 >= 0) & (s1 <= LDS_PITCH - 2)
                & (r0 >= 0) & (r1 <= WIN_ROWS - 1);
        int a0 = r0 * LDS_PITCH + s0;
        int a1 = r1 * LDS_PITCH + s1;
        if (!ok) { a0 = 0; a1 = 0; badmask |= (1 << i); }  // safe dummy; fixed up
        o0[i] = a0;  o1[i] = a1;
    }

    // ---- channel loop: ONE barrier per channel, stage 2 ahead -------------
    // Per-wave VMEM issue: [flo x2][stage0 x3][stage1 x3] | iter c: store(c),
    // stage(c+2) x3. At iter-c wait, newer than stage(c)'s last op:
    //   c==0 : stage(1) x3                    -> vmcnt(3)
    //   1..14: store(c-1) + stage(c+1) x3 = 4 -> vmcnt(4)  (store in flight)
    //   c==15: store(14)                      -> vmcnt(1)
    #pragma unroll
    for (int c = 0; c < CC; ++c) {
        const int buf = c % NBUF;

        if (c == 0)          asm volatile("s_waitcnt vmcnt(3)" ::: "memory");
        else if (c < CC - 1) asm volatile("s_waitcnt vmcnt(4)" ::: "memory");
        else                 asm volatile("s_waitcnt vmcnt(1)" ::: "memory");
        asm volatile("s_waitcnt lgkmcnt(0)" ::: "memory"); // reads of c-1 drained
        __builtin_amdgcn_sched_barrier(0);
        __builtin_amdgcn_s_barrier();   // all waves: stage(c) visible AND
                                        // everyone done reading buf((c-1)%3)

        const float* cur = lds + buf * PAD_FLOATS;
        f4 v;
        #pragma unroll
        for (int i = 0; i < 4; ++i) {
            float t0 = cur[o0[i]];
            float t1 = cur[o0[i] + 1];
            float u0 = cur[o1[i]];
            float u1 = cur[o1[i] + 1];
            v[i] = wtx[i] * t0 + wty[i] * t1 + wbx[i] * u0 + wby[i] * u1;
        }
        __builtin_nontemporal_store(v, (f4*)(outb + (size_t)c * HWSZ + hw));

        if (c + 2 < CC) stage(c + 2, (c + 2) % NBUF);  // overwrites buf((c-1)%3)
    }

    // ---- fixup: pixels whose footprint missed the staged window (~never) ---
    if (__builtin_expect(badmask != 0, 0)) {
        #pragma unroll
        for (int i = 0; i < 4; ++i) if (badmask & (1 << i)) {
            float fx = flo[(size_t)(b * 2 + 0) * HWSZ + hw + i];
            float fy = flo[(size_t)(b * 2 + 1) * HWSZ + hw + i];
            float pos_x = (float)(w0 + i) + fx;
            float pos_y = (float)h + fy;
            float x0f = floorf(pos_x), y0f = floorf(pos_y);
            float xw = pos_x - x0f,   yw = pos_y - y0f;
            int x0 = (int)fminf(fmaxf(x0f,        0.0f), (float)(WW - 1));
            int x1 = (int)fminf(fmaxf(x0f + 1.0f, 0.0f), (float)(WW - 1));
            int y0 = (int)fminf(fmaxf(y0f,        0.0f), (float)(HH - 1));
            int y1 = (int)fminf(fmaxf(y0f + 1.0f, 0.0f), (float)(HH - 1));
            float wa = (1.0f - xw) * (1.0f - yw);
            float wb = (1.0f - xw) * yw;
            float wc = xw * (1.0f - yw);
            float wd = xw * yw;
            for (int c = 0; c < CC; ++c) {
                const float* p = imgb + (size_t)c * HWSZ;
                float vv = wa * p[y0 * WW + x0] + wb * p[y1 * WW + x0]
                         + wc * p[y0 * WW + x1] + wd * p[y1 * WW + x1];
                outb[(size_t)c * HWSZ + hw + i] = vv;   // same thread: ordered
            }
        }
    }
}

extern "C" void kernel_launch(void* const* d_in, const int* in_sizes, int n_in,
                              void* d_out, int out_size, void* d_ws, size_t ws_size,
                              hipStream_t stream)
{
    const float* img = (const float*)d_in[0];
    const float* flo = (const float*)d_in[1];
    float*       out = (float*)d_out;

    warp_bilinear_kernel<<<NBLOCKS, 256, 0, stream>>>(img, flo, out);
}